// Round 2
// baseline (607.970 us; speedup 1.0000x reference)
//
#include <hip/hip_runtime.h>
#include <math.h>

// ---------------------------------------------------------------------------
// DecoderLayer fused implementation v2 (MI355X / gfx950)
//   K0: convert weights fp32 -> bf16 into ws
//   K1: per-node message MLP, barrier-free K-loop (direct global->reg MFMA
//       A-fragments), h_V term via broadcast-row MFMA, + edge-sum + LN1
//   K2: FFN (128->512->128) + LN2 + mask_V, 8-wave split, 512 blocks
// ---------------------------------------------------------------------------

typedef __bf16 bf16;
typedef __attribute__((ext_vector_type(8))) __bf16 bf16x8;
typedef __attribute__((ext_vector_type(4))) float f32x4;
typedef __attribute__((ext_vector_type(4))) unsigned uint4v;

// pack two fp32 -> two bf16 (round-half-away), 3 VALU ops
__device__ __forceinline__ unsigned pk2bf(float a, float b) {
    unsigned ua = __builtin_bit_cast(unsigned, a) + 0x8000u;
    unsigned ub = __builtin_bit_cast(unsigned, b) + 0x8000u;
    return __builtin_amdgcn_perm(ub, ua, 0x07060302u);  // [hi(ub)|hi(ua)]
}
__device__ __forceinline__ bf16 f2bf(float f) {
    unsigned short s = (unsigned short)((__builtin_bit_cast(unsigned, f) + 0x8000u) >> 16);
    return __builtin_bit_cast(bf16, s);
}
__device__ __forceinline__ bf16x8 pack8(float4 v0, float4 v1) {
    uint4v p;
    p.x = pk2bf(v0.x, v0.y); p.y = pk2bf(v0.z, v0.w);
    p.z = pk2bf(v1.x, v1.y); p.w = pk2bf(v1.z, v1.w);
    return __builtin_bit_cast(bf16x8, p);
}
// tanh-approx gelu as x*sigmoid(1.5958*(x+0.044715 x^3)); |err| vs erf-gelu < 3e-3
__device__ __forceinline__ float gelu_f(float x) {
    float u = 1.595769122f * x * fmaf(0.044715f, x * x, 1.0f);
    float e = __expf(-u);
    return x * __builtin_amdgcn_rcpf(1.0f + e);
}
__device__ __forceinline__ f32x4 mfma16(bf16x8 a, bf16x8 b, f32x4 c) {
    return __builtin_amdgcn_mfma_f32_16x16x32_bf16(a, b, c, 0, 0, 0);
}

// ws layout (bf16 elements):
#define WS_W2   65536
#define WS_W3   81920
#define WS_WIN  98304
#define WS_WOUT 163840
#define WS_TOTAL_W 229376
#define WS_H1_BYTES 458752

// ---------------------------------------------------------------------------
__global__ void convert_weights(const float* __restrict__ W1, const float* __restrict__ W2,
                                const float* __restrict__ W3, const float* __restrict__ Win,
                                const float* __restrict__ Wout, bf16* __restrict__ ws) {
    int i = blockIdx.x * 256 + threadIdx.x;
    if (i < WS_W2)              ws[i] = f2bf(W1[i]);
    else if (i < WS_W3)         ws[i] = f2bf(W2[i - WS_W2]);
    else if (i < WS_WIN)        ws[i] = f2bf(W3[i - WS_W3]);
    else if (i < WS_WOUT)       ws[i] = f2bf(Win[i - WS_WIN]);
    else if (i < WS_TOTAL_W)    ws[i] = f2bf(Wout[i - WS_WOUT]);
}

// ---------------------------------------------------------------------------
// K1: one node per block (48 edge rows), 256 threads (4 waves).
// Wave w owns output cols [w*32, w*32+32). Phase 1 has NO barriers: A-frags
// loaded straight from h_E (16 rows x 128B contiguous per load inst).
__global__ __launch_bounds__(256, 4)
void msg_kernel(const float* __restrict__ h_V, const float* __restrict__ h_E,
                const float* __restrict__ mask_attend,
                const bf16* __restrict__ W1b, const bf16* __restrict__ W2b,
                const bf16* __restrict__ W3b,
                const float* __restrict__ b1, const float* __restrict__ b2,
                const float* __restrict__ b3,
                const float* __restrict__ ln1g, const float* __restrict__ ln1b,
                float* __restrict__ h1out) {
    __shared__ __align__(16) bf16 m1[48 * 136];   // stride 136: rows 16B-aligned
    __shared__ __align__(16) bf16 m2[48 * 136];
    __shared__ float tbuf[128];

    const int tid  = threadIdx.x;
    const int wave = tid >> 6;
    const int lane = tid & 63;
    const int q    = lane >> 4;
    const int c15  = lane & 15;
    const int g    = blockIdx.x;
    const int n0c  = wave * 32 + c15;

    const f32x4 zero = {0.f, 0.f, 0.f, 0.f};

    // ---- prologue: y0 = h_V @ W1[:, :128]^T, broadcast into all 16 rows ----
    f32x4 acc0[2] = {zero, zero};
    {
        const float* pV  = h_V + (size_t)g * 128 + q * 8;
        const bf16* pWv0 = W1b + (size_t)n0c * 512 + q * 8;
        const bf16* pWv1 = pWv0 + 16 * 512;
#pragma unroll
        for (int s = 0; s < 4; ++s) {
            float4 v0 = *(const float4*)(pV + s * 32);
            float4 v1 = *(const float4*)(pV + s * 32 + 4);
            bf16x8 af = pack8(v0, v1);
            bf16x8 w0 = *(const bf16x8*)(pWv0 + s * 32);
            bf16x8 w1 = *(const bf16x8*)(pWv1 + s * 32);
            acc0[0] = mfma16(af, w0, acc0[0]);
            acc0[1] = mfma16(af, w1, acc0[1]);
        }
    }

    // ---- phase 1: h_E @ W1[:, 128:]^T, barrier-free ----
    f32x4 acc[3][2];
#pragma unroll
    for (int mt = 0; mt < 3; ++mt) { acc[mt][0] = zero; acc[mt][1] = zero; }
    {
        const float* pE0 = h_E + ((size_t)g * 48 + c15) * 384 + q * 8;
        const float* pE1 = pE0 + 16 * 384;
        const float* pE2 = pE1 + 16 * 384;
        const bf16* pW0 = W1b + (size_t)n0c * 512 + 128 + q * 8;
        const bf16* pW1 = pW0 + 16 * 512;
#pragma unroll
        for (int ks = 0; ks < 12; ++ks) {
            bf16x8 w0 = *(const bf16x8*)(pW0 + ks * 32);
            bf16x8 w1 = *(const bf16x8*)(pW1 + ks * 32);
            float4 a00 = *(const float4*)(pE0 + ks * 32);
            float4 a01 = *(const float4*)(pE0 + ks * 32 + 4);
            float4 a10 = *(const float4*)(pE1 + ks * 32);
            float4 a11 = *(const float4*)(pE1 + ks * 32 + 4);
            float4 a20 = *(const float4*)(pE2 + ks * 32);
            float4 a21 = *(const float4*)(pE2 + ks * 32 + 4);
            bf16x8 f0 = pack8(a00, a01);
            bf16x8 f1 = pack8(a10, a11);
            bf16x8 f2 = pack8(a20, a21);
            acc[0][0] = mfma16(f0, w0, acc[0][0]);
            acc[0][1] = mfma16(f0, w1, acc[0][1]);
            acc[1][0] = mfma16(f1, w0, acc[1][0]);
            acc[1][1] = mfma16(f1, w1, acc[1][1]);
            acc[2][0] = mfma16(f2, w0, acc[2][0]);
            acc[2][1] = mfma16(f2, w1, acc[2][1]);
        }
    }
    // epilogue 1: +y0 +b1, gelu -> m1
    {
        const float bb0 = b1[n0c], bb1 = b1[n0c + 16];
#pragma unroll
        for (int mt = 0; mt < 3; ++mt)
#pragma unroll
            for (int r = 0; r < 4; ++r) {
                const int row = mt * 16 + q * 4 + r;
                m1[row * 136 + n0c]      = f2bf(gelu_f(acc[mt][0][r] + acc0[0][r] + bb0));
                m1[row * 136 + n0c + 16] = f2bf(gelu_f(acc[mt][1][r] + acc0[1][r] + bb1));
            }
    }
    __syncthreads();

    // ---- phase 2: m1 @ W2^T, gelu -> m2 ----
    f32x4 acc2[3][2];
#pragma unroll
    for (int mt = 0; mt < 3; ++mt) { acc2[mt][0] = zero; acc2[mt][1] = zero; }
    {
        bf16x8 w[4][2];
        const bf16* pW20 = W2b + (size_t)n0c * 128 + q * 8;
        const bf16* pW21 = pW20 + 16 * 128;
#pragma unroll
        for (int s = 0; s < 4; ++s) {
            w[s][0] = *(const bf16x8*)(pW20 + s * 32);
            w[s][1] = *(const bf16x8*)(pW21 + s * 32);
        }
        const bf16* pA = m1 + c15 * 136 + q * 8;
#pragma unroll
        for (int s = 0; s < 4; ++s)
#pragma unroll
            for (int mt = 0; mt < 3; ++mt) {
                bf16x8 af = *(const bf16x8*)(pA + mt * 16 * 136 + s * 32);
                acc2[mt][0] = mfma16(af, w[s][0], acc2[mt][0]);
                acc2[mt][1] = mfma16(af, w[s][1], acc2[mt][1]);
            }
    }
    {
        const float bb0 = b2[n0c], bb1 = b2[n0c + 16];
#pragma unroll
        for (int mt = 0; mt < 3; ++mt)
#pragma unroll
            for (int r = 0; r < 4; ++r) {
                const int row = mt * 16 + q * 4 + r;
                m2[row * 136 + n0c]      = f2bf(gelu_f(acc2[mt][0][r] + bb0));
                m2[row * 136 + n0c + 16] = f2bf(gelu_f(acc2[mt][1][r] + bb1));
            }
    }
    __syncthreads();

    // ---- phase 3: m2 @ W3^T, +b3, *mask, edge-sum ----
    f32x4 acc3[3][2];
#pragma unroll
    for (int mt = 0; mt < 3; ++mt) { acc3[mt][0] = zero; acc3[mt][1] = zero; }
    {
        bf16x8 w[4][2];
        const bf16* pW30 = W3b + (size_t)n0c * 128 + q * 8;
        const bf16* pW31 = pW30 + 16 * 128;
#pragma unroll
        for (int s = 0; s < 4; ++s) {
            w[s][0] = *(const bf16x8*)(pW30 + s * 32);
            w[s][1] = *(const bf16x8*)(pW31 + s * 32);
        }
        const bf16* pA = m2 + c15 * 136 + q * 8;
#pragma unroll
        for (int s = 0; s < 4; ++s)
#pragma unroll
            for (int mt = 0; mt < 3; ++mt) {
                bf16x8 af = *(const bf16x8*)(pA + mt * 16 * 136 + s * 32);
                acc3[mt][0] = mfma16(af, w[s][0], acc3[mt][0]);
                acc3[mt][1] = mfma16(af, w[s][1], acc3[mt][1]);
            }
    }
    {
        const float bb0 = b3[n0c], bb1 = b3[n0c + 16];
        float s0 = 0.f, s1 = 0.f;
#pragma unroll
        for (int mt = 0; mt < 3; ++mt)
#pragma unroll
            for (int r = 0; r < 4; ++r) {
                const int row = mt * 16 + q * 4 + r;
                const float mv = mask_attend[(size_t)g * 48 + row];
                s0 += (acc3[mt][0][r] + bb0) * mv;
                s1 += (acc3[mt][1][r] + bb1) * mv;
            }
        s0 += __shfl_xor(s0, 16); s0 += __shfl_xor(s0, 32);
        s1 += __shfl_xor(s1, 16); s1 += __shfl_xor(s1, 32);
        if (lane < 16) {
            tbuf[n0c]      = h_V[(size_t)g * 128 + n0c]      + s0 * (1.0f / 30.0f);
            tbuf[n0c + 16] = h_V[(size_t)g * 128 + n0c + 16] + s1 * (1.0f / 30.0f);
        }
    }
    __syncthreads();

    // ---- LN1 (wave 0) ----
    if (wave == 0) {
        const float x0 = tbuf[lane];
        const float x1 = tbuf[lane + 64];
        float sm = x0 + x1, sq = x0 * x0 + x1 * x1;
#pragma unroll
        for (int off = 1; off < 64; off <<= 1) { sm += __shfl_xor(sm, off); sq += __shfl_xor(sq, off); }
        const float mu  = sm * (1.0f / 128.0f);
        const float var = sq * (1.0f / 128.0f) - mu * mu;
        const float inv = rsqrtf(var + 1e-5f);
        h1out[(size_t)g * 128 + lane]      = (x0 - mu) * inv * ln1g[lane]      + ln1b[lane];
        h1out[(size_t)g * 128 + 64 + lane] = (x1 - mu) * inv * ln1g[64 + lane] + ln1b[64 + lane];
    }
}

// ---------------------------------------------------------------------------
// K2: FFN + LN2 + mask_V. 512 blocks x 512 threads; block computes a 16-row
// tile (rows blk*8 .. blk*8+16, clamped) but writes only its own 8 rows.
__global__ __launch_bounds__(512, 4)
void ffn_kernel(const float* __restrict__ h1, const bf16* __restrict__ Winb,
                const bf16* __restrict__ Woutb,
                const float* __restrict__ bin, const float* __restrict__ bout,
                const float* __restrict__ ln2g, const float* __restrict__ ln2b,
                const float* __restrict__ mask_V, float* __restrict__ out) {
    __shared__ __align__(16) bf16 a2[16 * 136];
    __shared__ __align__(16) bf16 ff[16 * 520];
    __shared__ float tb0[16 * 132];
    __shared__ float tb1[16 * 132];

    const int tid  = threadIdx.x;
    const int wave = tid >> 6;      // 0..7
    const int lane = tid & 63;
    const int q    = lane >> 4;
    const int c15  = lane & 15;
    const int r0g  = blockIdx.x * 8;
    const f32x4 zero = {0.f, 0.f, 0.f, 0.f};

    // stage 16 rows of h1 -> bf16 LDS
    {
        const int row = tid >> 5;         // 0..15
        const int c4  = tid & 31;
        const int gr  = min(r0g + row, 4095);
        float4 v = *(const float4*)(h1 + (size_t)gr * 128 + c4 * 4);
        uint2 pk; pk.x = pk2bf(v.x, v.y); pk.y = pk2bf(v.z, v.w);
        *(uint2*)(a2 + row * 136 + c4 * 4) = pk;
    }
    __syncthreads();

    // GEMM-a: wave w -> ff cols [w*64, w*64+64)
    {
        f32x4 accA[4] = {zero, zero, zero, zero};
        const bf16* pA = a2 + c15 * 136 + q * 8;
#pragma unroll
        for (int s = 0; s < 4; ++s) {
            bf16x8 af = *(const bf16x8*)(pA + s * 32);
#pragma unroll
            for (int nt = 0; nt < 4; ++nt) {
                const int n = wave * 64 + nt * 16 + c15;
                bf16x8 wb = *(const bf16x8*)(Winb + (size_t)n * 128 + s * 32 + q * 8);
                accA[nt] = mfma16(af, wb, accA[nt]);
            }
        }
#pragma unroll
        for (int nt = 0; nt < 4; ++nt) {
            const int col = wave * 64 + nt * 16 + c15;
            const float bb = bin[col];
#pragma unroll
            for (int r = 0; r < 4; ++r)
                ff[(q * 4 + r) * 520 + col] = f2bf(gelu_f(accA[nt][r] + bb));
        }
    }
    __syncthreads();

    // GEMM-b: wave -> (k-half, n-quarter); partials into tb0/tb1
    {
        const int kh = wave & 1, nq = wave >> 1;
        f32x4 accB[2] = {zero, zero};
        const bf16* pF = ff + c15 * 520 + kh * 256 + q * 8;
#pragma unroll
        for (int s = 0; s < 8; ++s) {
            bf16x8 af = *(const bf16x8*)(pF + s * 32);
#pragma unroll
            for (int nt = 0; nt < 2; ++nt) {
                const int n = nq * 32 + nt * 16 + c15;
                bf16x8 wb = *(const bf16x8*)(Woutb + (size_t)n * 512 + kh * 256 + s * 32 + q * 8);
                accB[nt] = mfma16(af, wb, accB[nt]);
            }
        }
        float* tb = kh ? tb1 : tb0;
#pragma unroll
        for (int nt = 0; nt < 2; ++nt) {
            const int col = nq * 32 + nt * 16 + c15;
#pragma unroll
            for (int r = 0; r < 4; ++r) {
                const int row = q * 4 + r;
                float v = accB[nt][r];
                if (kh == 0) {
                    const int gr = min(r0g + row, 4095);
                    v += bout[col] + h1[(size_t)gr * 128 + col];
                }
                tb[row * 132 + col] = v;
            }
        }
    }
    __syncthreads();

    // LN2 + mask: wave w -> row w (first 8 rows only)
    {
        const int row = wave;
        const int gr  = r0g + row;
        const float x0 = tb0[row * 132 + lane]      + tb1[row * 132 + lane];
        const float x1 = tb0[row * 132 + 64 + lane] + tb1[row * 132 + 64 + lane];
        float sm = x0 + x1, sq = x0 * x0 + x1 * x1;
#pragma unroll
        for (int off = 1; off < 64; off <<= 1) { sm += __shfl_xor(sm, off); sq += __shfl_xor(sq, off); }
        const float mu  = sm * (1.0f / 128.0f);
        const float var = sq * (1.0f / 128.0f) - mu * mu;
        const float inv = rsqrtf(var + 1e-5f);
        const float mv  = mask_V[gr];
        out[(size_t)gr * 128 + lane]      = mv * ((x0 - mu) * inv * ln2g[lane]      + ln2b[lane]);
        out[(size_t)gr * 128 + 64 + lane] = mv * ((x1 - mu) * inv * ln2g[64 + lane] + ln2b[64 + lane]);
    }
}

// ---------------------------------------------------------------------------
extern "C" void kernel_launch(void* const* d_in, const int* in_sizes, int n_in,
                              void* d_out, int out_size, void* d_ws, size_t ws_size,
                              hipStream_t stream) {
    const float* h_V         = (const float*)d_in[0];
    const float* h_E         = (const float*)d_in[1];
    const float* mask_V      = (const float*)d_in[2];
    const float* mask_attend = (const float*)d_in[3];
    const float* W1w  = (const float*)d_in[4];
    const float* W1bb = (const float*)d_in[5];
    const float* W2w  = (const float*)d_in[6];
    const float* W2bb = (const float*)d_in[7];
    const float* W3w  = (const float*)d_in[8];
    const float* W3bb = (const float*)d_in[9];
    const float* ln1g = (const float*)d_in[10];
    const float* ln1b = (const float*)d_in[11];
    const float* ln2g = (const float*)d_in[12];
    const float* ln2b = (const float*)d_in[13];
    const float* Winw  = (const float*)d_in[14];
    const float* Winbb = (const float*)d_in[15];
    const float* Woutw  = (const float*)d_in[16];
    const float* Woutbb = (const float*)d_in[17];

    bf16* wsb   = (bf16*)d_ws;
    bf16* W1c   = wsb;
    bf16* W2c   = wsb + WS_W2;
    bf16* W3c   = wsb + WS_W3;
    bf16* Winc  = wsb + WS_WIN;
    bf16* Woutc = wsb + WS_WOUT;
    float* h1   = (float*)((char*)d_ws + WS_H1_BYTES);

    convert_weights<<<896, 256, 0, stream>>>(W1w, W2w, W3w, Winw, Woutw, wsb);
    msg_kernel<<<4096, 256, 0, stream>>>(h_V, h_E, mask_attend, W1c, W2c, W3c,
                                         W1bb, W2bb, W3bb, ln1g, ln1b, h1);
    ffn_kernel<<<512, 512, 0, stream>>>(h1, Winc, Woutc, Winbb, Woutbb,
                                        ln2g, ln2b, mask_V, (float*)d_out);
}

// Round 4
// 570.617 us; speedup vs baseline: 1.0655x; 1.0655x over previous
//
#include <hip/hip_runtime.h>
#include <math.h>

// ---------------------------------------------------------------------------
// DecoderLayer fused implementation v3.1 (MI355X / gfx950)
//   K0 : convert weights fp32 -> bf16 into ws
//   K0b: convert h_E fp32 -> bf16 into ws (streaming, BW-bound)  [grid FIXED]
//   K1 : msg kernel reading bf16 h_E via single-shot global_load_lds DMA,
//        swizzled LDS, barrier-free K-loop, 3 blocks/CU
//   K1f: fallback msg kernel (v2, fp32 h_E) if ws too small for h_Eb
//   K2 : FFN (128->512->128) + LN2 + mask_V, 256 blocks, packs h1 on stage
// ---------------------------------------------------------------------------

typedef __bf16 bf16;
typedef __attribute__((ext_vector_type(8))) __bf16 bf16x8;
typedef __attribute__((ext_vector_type(4))) float f32x4;
typedef __attribute__((ext_vector_type(4))) unsigned uint4v;

__device__ __forceinline__ unsigned pk2bf(float a, float b) {
    unsigned ua = __builtin_bit_cast(unsigned, a) + 0x8000u;
    unsigned ub = __builtin_bit_cast(unsigned, b) + 0x8000u;
    return __builtin_amdgcn_perm(ub, ua, 0x07060302u);
}
__device__ __forceinline__ bf16 f2bf(float f) {
    unsigned short s = (unsigned short)((__builtin_bit_cast(unsigned, f) + 0x8000u) >> 16);
    return __builtin_bit_cast(bf16, s);
}
__device__ __forceinline__ bf16x8 pack8(float4 v0, float4 v1) {
    uint4v p;
    p.x = pk2bf(v0.x, v0.y); p.y = pk2bf(v0.z, v0.w);
    p.z = pk2bf(v1.x, v1.y); p.w = pk2bf(v1.z, v1.w);
    return __builtin_bit_cast(bf16x8, p);
}
__device__ __forceinline__ float gelu_f(float x) {
    float u = 1.595769122f * x * fmaf(0.044715f, x * x, 1.0f);
    float e = __expf(-u);
    return x * __builtin_amdgcn_rcpf(1.0f + e);
}
__device__ __forceinline__ f32x4 mfma16(bf16x8 a, bf16x8 b, f32x4 c) {
    return __builtin_amdgcn_mfma_f32_16x16x32_bf16(a, b, c, 0, 0, 0);
}
__device__ __forceinline__ void dma16(const void* g, void* l) {
    __builtin_amdgcn_global_load_lds(
        (const __attribute__((address_space(1))) unsigned int*)g,
        (__attribute__((address_space(3))) unsigned int*)l, 16, 0, 0);
}

// ws layout (bytes):
//   weights bf16 @ 0        : 458752
//   h1 fp32      @ 458752   : 2097152   (ends 2555904)
//   h_Eb bf16    @ 2555904  : 150994944 (main path only; 75,497,472 elems)
#define WS_W2   65536
#define WS_W3   81920
#define WS_WIN  98304
#define WS_WOUT 163840
#define WS_TOTAL_W 229376
#define WS_H1_OFF  458752
#define WS_HEB_OFF 2555904ull

// ---------------------------------------------------------------------------
__global__ void convert_weights(const float* __restrict__ W1, const float* __restrict__ W2,
                                const float* __restrict__ W3, const float* __restrict__ Win,
                                const float* __restrict__ Wout, bf16* __restrict__ ws) {
    int i = blockIdx.x * 256 + threadIdx.x;
    if (i < WS_W2)              ws[i] = f2bf(W1[i]);
    else if (i < WS_W3)         ws[i] = f2bf(W2[i - WS_W2]);
    else if (i < WS_WIN)        ws[i] = f2bf(W3[i - WS_W3]);
    else if (i < WS_WOUT)       ws[i] = f2bf(Win[i - WS_WIN]);
    else if (i < WS_TOTAL_W)    ws[i] = f2bf(Wout[i - WS_WOUT]);
}

// streaming fp32 -> bf16 of h_E: 8 elements/thread, guarded
__global__ void convert_hE(const float* __restrict__ he, bf16* __restrict__ out, long long n) {
    size_t i = ((size_t)blockIdx.x * 256 + threadIdx.x) * 8;
    if ((long long)i + 8 > n) return;
    float4 v0 = *(const float4*)(he + i);
    float4 v1 = *(const float4*)(he + i + 4);
    *(bf16x8*)(out + i) = pack8(v0, v1);
}

// ---------------------------------------------------------------------------
// K1 main: one node per block, 256 threads (4 waves), N-split 32 cols/wave.
// Single-shot 36KB DMA of the node's bf16 h_E rows into swizzled LDS.
// LDS swizzle: row r (768B), 16B-seg s stored at p = (s&48)|((s&15)^(r&15)).
__global__ __launch_bounds__(256, 3)
void msg_kernel_b(const float* __restrict__ h_V, const bf16* __restrict__ hEb,
                  const float* __restrict__ mask_attend,
                  const bf16* __restrict__ W1b, const bf16* __restrict__ W2b,
                  const bf16* __restrict__ W3b,
                  const float* __restrict__ b1, const float* __restrict__ b2,
                  const float* __restrict__ b3,
                  const float* __restrict__ ln1g, const float* __restrict__ ln1b,
                  float* __restrict__ h1out) {
    __shared__ __align__(16) char smem[50432];
    bf16*  Ab   = (bf16*)smem;            // [48][384] swizzled (36864 B), dead after phase1
    bf16*  m2   = (bf16*)smem;            // [48][136] aliases Ab
    bf16*  m1   = (bf16*)(smem + 36864);  // [48][136] = 13056 B
    float* tbuf = (float*)(smem + 49920); // 128 fp32

    const int tid  = threadIdx.x;
    const int wave = tid >> 6;
    const int lane = tid & 63;
    const int q    = lane >> 4;
    const int c15  = lane & 15;
    const int g    = blockIdx.x;
    const int n0c  = wave * 32 + c15;
    const f32x4 zero = {0.f, 0.f, 0.f, 0.f};

    // ---- prologue loads first ----
    float4 pv0[4], pv1[4];
    bf16x8 pw0[4], pw1[4];
    {
        const float* pV  = h_V + (size_t)g * 128 + q * 8;
        const bf16* pWv0 = W1b + (size_t)n0c * 512 + q * 8;
        const bf16* pWv1 = pWv0 + 16 * 512;
#pragma unroll
        for (int s = 0; s < 4; ++s) {
            pv0[s] = *(const float4*)(pV + s * 32);
            pv1[s] = *(const float4*)(pV + s * 32 + 4);
            pw0[s] = *(const bf16x8*)(pWv0 + s * 32);
            pw1[s] = *(const bf16x8*)(pWv1 + s * 32);
        }
    }

    // ---- issue single-shot DMA: 36 KB = 36 wave-issues (9 per wave) ----
    {
        const bf16* eb = hEb + (size_t)g * 48 * 384;
#pragma unroll
        for (int i = 0; i < 9; ++i) {
            const int off = wave * 9216 + i * 1024 + lane * 16;  // byte offset in 36864
            const int x   = off >> 8;
            const int row = (x * 21846) >> 16;                   // off / 768
            const int seg = (off - row * 768) >> 4;              // 0..47
            const int ss  = (seg & 48) | ((seg & 15) ^ (row & 15));
            dma16(eb + row * 384 + ss * 8, smem + wave * 9216 + i * 1024);
        }
    }

    // ---- prologue compute: y0 = h_V @ W1[:, :128]^T (broadcast rows) ----
    f32x4 acc0[2] = {zero, zero};
#pragma unroll
    for (int s = 0; s < 4; ++s) {
        bf16x8 af = pack8(pv0[s], pv1[s]);
        acc0[0] = mfma16(af, pw0[s], acc0[0]);
        acc0[1] = mfma16(af, pw1[s], acc0[1]);
    }
    __syncthreads();   // drains DMA

    // ---- phase 1: h_E @ W1[:, 128:]^T, zero barriers ----
    f32x4 acc[3][2];
#pragma unroll
    for (int mt = 0; mt < 3; ++mt) { acc[mt][0] = zero; acc[mt][1] = zero; }
    {
        const bf16* pW0 = W1b + (size_t)n0c * 512 + 128 + q * 8;
        const bf16* pW1 = pW0 + 16 * 512;
#pragma unroll
        for (int s = 0; s < 12; ++s) {
            bf16x8 w0 = *(const bf16x8*)(pW0 + s * 32);
            bf16x8 w1 = *(const bf16x8*)(pW1 + s * 32);
            const int sq = s * 4 + q;
            const int p  = (sq & 48) | ((sq & 15) ^ c15);
#pragma unroll
            for (int mt = 0; mt < 3; ++mt) {
                bf16x8 af = *(const bf16x8*)(Ab + (mt * 16 + c15) * 384 + p * 8);
                acc[mt][0] = mfma16(af, w0, acc[mt][0]);
                acc[mt][1] = mfma16(af, w1, acc[mt][1]);
            }
        }
    }
    // epilogue 1: +y0 +b1, gelu -> m1
    {
        const float bb0 = b1[n0c], bb1 = b1[n0c + 16];
#pragma unroll
        for (int mt = 0; mt < 3; ++mt)
#pragma unroll
            for (int r = 0; r < 4; ++r) {
                const int row = mt * 16 + q * 4 + r;
                m1[row * 136 + n0c]      = f2bf(gelu_f(acc[mt][0][r] + acc0[0][r] + bb0));
                m1[row * 136 + n0c + 16] = f2bf(gelu_f(acc[mt][1][r] + acc0[1][r] + bb1));
            }
    }
    __syncthreads();   // phase-1 reads of Ab done; m2 may overwrite

    // ---- phase 2: m1 @ W2^T, gelu -> m2 ----
    f32x4 acc2[3][2];
#pragma unroll
    for (int mt = 0; mt < 3; ++mt) { acc2[mt][0] = zero; acc2[mt][1] = zero; }
    {
        bf16x8 w[4][2];
        const bf16* pW20 = W2b + (size_t)n0c * 128 + q * 8;
        const bf16* pW21 = pW20 + 16 * 128;
#pragma unroll
        for (int s = 0; s < 4; ++s) {
            w[s][0] = *(const bf16x8*)(pW20 + s * 32);
            w[s][1] = *(const bf16x8*)(pW21 + s * 32);
        }
        const bf16* pA = m1 + c15 * 136 + q * 8;
#pragma unroll
        for (int s = 0; s < 4; ++s)
#pragma unroll
            for (int mt = 0; mt < 3; ++mt) {
                bf16x8 af = *(const bf16x8*)(pA + mt * 16 * 136 + s * 32);
                acc2[mt][0] = mfma16(af, w[s][0], acc2[mt][0]);
                acc2[mt][1] = mfma16(af, w[s][1], acc2[mt][1]);
            }
    }
    {
        const float bb0 = b2[n0c], bb1 = b2[n0c + 16];
#pragma unroll
        for (int mt = 0; mt < 3; ++mt)
#pragma unroll
            for (int r = 0; r < 4; ++r) {
                const int row = mt * 16 + q * 4 + r;
                m2[row * 136 + n0c]      = f2bf(gelu_f(acc2[mt][0][r] + bb0));
                m2[row * 136 + n0c + 16] = f2bf(gelu_f(acc2[mt][1][r] + bb1));
            }
    }
    __syncthreads();

    // ---- phase 3: m2 @ W3^T, +b3, *mask, edge-sum ----
    f32x4 acc3[3][2];
#pragma unroll
    for (int mt = 0; mt < 3; ++mt) { acc3[mt][0] = zero; acc3[mt][1] = zero; }
    {
        bf16x8 w[4][2];
        const bf16* pW30 = W3b + (size_t)n0c * 128 + q * 8;
        const bf16* pW31 = pW30 + 16 * 128;
#pragma unroll
        for (int s = 0; s < 4; ++s) {
            w[s][0] = *(const bf16x8*)(pW30 + s * 32);
            w[s][1] = *(const bf16x8*)(pW31 + s * 32);
        }
        const bf16* pA = m2 + c15 * 136 + q * 8;
#pragma unroll
        for (int s = 0; s < 4; ++s)
#pragma unroll
            for (int mt = 0; mt < 3; ++mt) {
                bf16x8 af = *(const bf16x8*)(pA + mt * 16 * 136 + s * 32);
                acc3[mt][0] = mfma16(af, w[s][0], acc3[mt][0]);
                acc3[mt][1] = mfma16(af, w[s][1], acc3[mt][1]);
            }
    }
    {
        const float bb0 = b3[n0c], bb1 = b3[n0c + 16];
        float s0 = 0.f, s1 = 0.f;
#pragma unroll
        for (int mt = 0; mt < 3; ++mt)
#pragma unroll
            for (int r = 0; r < 4; ++r) {
                const int row = mt * 16 + q * 4 + r;
                const float mv = mask_attend[(size_t)g * 48 + row];
                s0 += (acc3[mt][0][r] + bb0) * mv;
                s1 += (acc3[mt][1][r] + bb1) * mv;
            }
        s0 += __shfl_xor(s0, 16); s0 += __shfl_xor(s0, 32);
        s1 += __shfl_xor(s1, 16); s1 += __shfl_xor(s1, 32);
        if (lane < 16) {
            tbuf[n0c]      = h_V[(size_t)g * 128 + n0c]      + s0 * (1.0f / 30.0f);
            tbuf[n0c + 16] = h_V[(size_t)g * 128 + n0c + 16] + s1 * (1.0f / 30.0f);
        }
    }
    __syncthreads();

    if (wave == 0) {
        const float x0 = tbuf[lane];
        const float x1 = tbuf[lane + 64];
        float sm = x0 + x1, sq = x0 * x0 + x1 * x1;
#pragma unroll
        for (int off = 1; off < 64; off <<= 1) { sm += __shfl_xor(sm, off); sq += __shfl_xor(sq, off); }
        const float mu  = sm * (1.0f / 128.0f);
        const float var = sq * (1.0f / 128.0f) - mu * mu;
        const float inv = rsqrtf(var + 1e-5f);
        h1out[(size_t)g * 128 + lane]      = (x0 - mu) * inv * ln1g[lane]      + ln1b[lane];
        h1out[(size_t)g * 128 + 64 + lane] = (x1 - mu) * inv * ln1g[64 + lane] + ln1b[64 + lane];
    }
}

// ---------------------------------------------------------------------------
// K1 fallback (v2, fp32 h_E direct) — used only if ws too small for h_Eb.
__global__ __launch_bounds__(256, 4)
void msg_kernel(const float* __restrict__ h_V, const float* __restrict__ h_E,
                const float* __restrict__ mask_attend,
                const bf16* __restrict__ W1b, const bf16* __restrict__ W2b,
                const bf16* __restrict__ W3b,
                const float* __restrict__ b1, const float* __restrict__ b2,
                const float* __restrict__ b3,
                const float* __restrict__ ln1g, const float* __restrict__ ln1b,
                float* __restrict__ h1out) {
    __shared__ __align__(16) bf16 m1[48 * 136];
    __shared__ __align__(16) bf16 m2[48 * 136];
    __shared__ float tbuf[128];

    const int tid  = threadIdx.x;
    const int wave = tid >> 6;
    const int lane = tid & 63;
    const int q    = lane >> 4;
    const int c15  = lane & 15;
    const int g    = blockIdx.x;
    const int n0c  = wave * 32 + c15;
    const f32x4 zero = {0.f, 0.f, 0.f, 0.f};

    f32x4 acc0[2] = {zero, zero};
    {
        const float* pV  = h_V + (size_t)g * 128 + q * 8;
        const bf16* pWv0 = W1b + (size_t)n0c * 512 + q * 8;
        const bf16* pWv1 = pWv0 + 16 * 512;
#pragma unroll
        for (int s = 0; s < 4; ++s) {
            float4 v0 = *(const float4*)(pV + s * 32);
            float4 v1 = *(const float4*)(pV + s * 32 + 4);
            bf16x8 af = pack8(v0, v1);
            acc0[0] = mfma16(af, *(const bf16x8*)(pWv0 + s * 32), acc0[0]);
            acc0[1] = mfma16(af, *(const bf16x8*)(pWv1 + s * 32), acc0[1]);
        }
    }
    f32x4 acc[3][2];
#pragma unroll
    for (int mt = 0; mt < 3; ++mt) { acc[mt][0] = zero; acc[mt][1] = zero; }
    {
        const float* pE0 = h_E + ((size_t)g * 48 + c15) * 384 + q * 8;
        const float* pE1 = pE0 + 16 * 384;
        const float* pE2 = pE1 + 16 * 384;
        const bf16* pW0 = W1b + (size_t)n0c * 512 + 128 + q * 8;
        const bf16* pW1 = pW0 + 16 * 512;
#pragma unroll
        for (int ks = 0; ks < 12; ++ks) {
            bf16x8 w0 = *(const bf16x8*)(pW0 + ks * 32);
            bf16x8 w1 = *(const bf16x8*)(pW1 + ks * 32);
            bf16x8 f0 = pack8(*(const float4*)(pE0 + ks * 32), *(const float4*)(pE0 + ks * 32 + 4));
            bf16x8 f1 = pack8(*(const float4*)(pE1 + ks * 32), *(const float4*)(pE1 + ks * 32 + 4));
            bf16x8 f2 = pack8(*(const float4*)(pE2 + ks * 32), *(const float4*)(pE2 + ks * 32 + 4));
            acc[0][0] = mfma16(f0, w0, acc[0][0]); acc[0][1] = mfma16(f0, w1, acc[0][1]);
            acc[1][0] = mfma16(f1, w0, acc[1][0]); acc[1][1] = mfma16(f1, w1, acc[1][1]);
            acc[2][0] = mfma16(f2, w0, acc[2][0]); acc[2][1] = mfma16(f2, w1, acc[2][1]);
        }
    }
    {
        const float bb0 = b1[n0c], bb1 = b1[n0c + 16];
#pragma unroll
        for (int mt = 0; mt < 3; ++mt)
#pragma unroll
            for (int r = 0; r < 4; ++r) {
                const int row = mt * 16 + q * 4 + r;
                m1[row * 136 + n0c]      = f2bf(gelu_f(acc[mt][0][r] + acc0[0][r] + bb0));
                m1[row * 136 + n0c + 16] = f2bf(gelu_f(acc[mt][1][r] + acc0[1][r] + bb1));
            }
    }
    __syncthreads();
    f32x4 acc2[3][2];
#pragma unroll
    for (int mt = 0; mt < 3; ++mt) { acc2[mt][0] = zero; acc2[mt][1] = zero; }
    {
        bf16x8 w[4][2];
        const bf16* pW20 = W2b + (size_t)n0c * 128 + q * 8;
        const bf16* pW21 = pW20 + 16 * 128;
#pragma unroll
        for (int s = 0; s < 4; ++s) { w[s][0] = *(const bf16x8*)(pW20 + s * 32); w[s][1] = *(const bf16x8*)(pW21 + s * 32); }
        const bf16* pA = m1 + c15 * 136 + q * 8;
#pragma unroll
        for (int s = 0; s < 4; ++s)
#pragma unroll
            for (int mt = 0; mt < 3; ++mt) {
                bf16x8 af = *(const bf16x8*)(pA + mt * 16 * 136 + s * 32);
                acc2[mt][0] = mfma16(af, w[s][0], acc2[mt][0]);
                acc2[mt][1] = mfma16(af, w[s][1], acc2[mt][1]);
            }
    }
    {
        const float bb0 = b2[n0c], bb1 = b2[n0c + 16];
#pragma unroll
        for (int mt = 0; mt < 3; ++mt)
#pragma unroll
            for (int r = 0; r < 4; ++r) {
                const int row = mt * 16 + q * 4 + r;
                m2[row * 136 + n0c]      = f2bf(gelu_f(acc2[mt][0][r] + bb0));
                m2[row * 136 + n0c + 16] = f2bf(gelu_f(acc2[mt][1][r] + bb1));
            }
    }
    __syncthreads();
    f32x4 acc3[3][2];
#pragma unroll
    for (int mt = 0; mt < 3; ++mt) { acc3[mt][0] = zero; acc3[mt][1] = zero; }
    {
        bf16x8 w[4][2];
        const bf16* pW30 = W3b + (size_t)n0c * 128 + q * 8;
        const bf16* pW31 = pW30 + 16 * 128;
#pragma unroll
        for (int s = 0; s < 4; ++s) { w[s][0] = *(const bf16x8*)(pW30 + s * 32); w[s][1] = *(const bf16x8*)(pW31 + s * 32); }
        const bf16* pA = m2 + c15 * 136 + q * 8;
#pragma unroll
        for (int s = 0; s < 4; ++s)
#pragma unroll
            for (int mt = 0; mt < 3; ++mt) {
                bf16x8 af = *(const bf16x8*)(pA + mt * 16 * 136 + s * 32);
                acc3[mt][0] = mfma16(af, w[s][0], acc3[mt][0]);
                acc3[mt][1] = mfma16(af, w[s][1], acc3[mt][1]);
            }
    }
    {
        const float bb0 = b3[n0c], bb1 = b3[n0c + 16];
        float s0 = 0.f, s1 = 0.f;
#pragma unroll
        for (int mt = 0; mt < 3; ++mt)
#pragma unroll
            for (int r = 0; r < 4; ++r) {
                const int row = mt * 16 + q * 4 + r;
                const float mv = mask_attend[(size_t)g * 48 + row];
                s0 += (acc3[mt][0][r] + bb0) * mv;
                s1 += (acc3[mt][1][r] + bb1) * mv;
            }
        s0 += __shfl_xor(s0, 16); s0 += __shfl_xor(s0, 32);
        s1 += __shfl_xor(s1, 16); s1 += __shfl_xor(s1, 32);
        if (lane < 16) {
            tbuf[n0c]      = h_V[(size_t)g * 128 + n0c]      + s0 * (1.0f / 30.0f);
            tbuf[n0c + 16] = h_V[(size_t)g * 128 + n0c + 16] + s1 * (1.0f / 30.0f);
        }
    }
    __syncthreads();
    if (wave == 0) {
        const float x0 = tbuf[lane];
        const float x1 = tbuf[lane + 64];
        float sm = x0 + x1, sq = x0 * x0 + x1 * x1;
#pragma unroll
        for (int off = 1; off < 64; off <<= 1) { sm += __shfl_xor(sm, off); sq += __shfl_xor(sq, off); }
        const float mu  = sm * (1.0f / 128.0f);
        const float var = sq * (1.0f / 128.0f) - mu * mu;
        const float inv = rsqrtf(var + 1e-5f);
        h1out[(size_t)g * 128 + lane]      = (x0 - mu) * inv * ln1g[lane]      + ln1b[lane];
        h1out[(size_t)g * 128 + 64 + lane] = (x1 - mu) * inv * ln1g[64 + lane] + ln1b[64 + lane];
    }
}

// ---------------------------------------------------------------------------
// K2: FFN + LN2 + mask. 256 blocks x 256 threads, one 16-row tile per block.
__global__ __launch_bounds__(256)
void ffn_kernel(const float* __restrict__ h1, const bf16* __restrict__ Winb,
                const bf16* __restrict__ Woutb,
                const float* __restrict__ bin, const float* __restrict__ bout,
                const float* __restrict__ ln2g, const float* __restrict__ ln2b,
                const float* __restrict__ mask_V, float* __restrict__ out) {
    __shared__ __align__(16) bf16 a2[16 * 136];
    __shared__ __align__(16) bf16 ff[16 * 520];
    __shared__ float tb[16 * 132];

    const int tid  = threadIdx.x;
    const int wave = tid >> 6;
    const int lane = tid & 63;
    const int q    = lane >> 4;
    const int c15  = lane & 15;
    const int r0g  = blockIdx.x * 16;
    const f32x4 zero = {0.f, 0.f, 0.f, 0.f};

    // stage + pack h1 -> bf16 LDS
    {
        const int row = tid >> 4, seg = tid & 15;
        const float* p = h1 + (size_t)(r0g + row) * 128 + seg * 8;
        float4 v0 = *(const float4*)p, v1 = *(const float4*)(p + 4);
        *(bf16x8*)(a2 + row * 136 + seg * 8) = pack8(v0, v1);
    }
    __syncthreads();

    // GEMM-a: wave w -> ff cols [w*128, +128)
    {
        f32x4 accA[8];
#pragma unroll
        for (int i = 0; i < 8; ++i) accA[i] = zero;
#pragma unroll
        for (int s = 0; s < 4; ++s) {
            bf16x8 af = *(const bf16x8*)(a2 + c15 * 136 + s * 32 + q * 8);
#pragma unroll
            for (int nt = 0; nt < 8; ++nt) {
                const int n = wave * 128 + nt * 16 + c15;
                bf16x8 wb = *(const bf16x8*)(Winb + (size_t)n * 128 + s * 32 + q * 8);
                accA[nt] = mfma16(af, wb, accA[nt]);
            }
        }
#pragma unroll
        for (int nt = 0; nt < 8; ++nt) {
            const int col = wave * 128 + nt * 16 + c15;
            const float bb = bin[col];
#pragma unroll
            for (int r = 0; r < 4; ++r)
                ff[(q * 4 + r) * 520 + col] = f2bf(gelu_f(accA[nt][r] + bb));
        }
    }
    __syncthreads();

    // GEMM-b: wave w -> out cols [w*32, +32), full K=512
    {
        f32x4 accB[2] = {zero, zero};
#pragma unroll
        for (int s = 0; s < 16; ++s) {
            bf16x8 af = *(const bf16x8*)(ff + c15 * 520 + s * 32 + q * 8);
#pragma unroll
            for (int nt = 0; nt < 2; ++nt) {
                const int n = wave * 32 + nt * 16 + c15;
                bf16x8 wb = *(const bf16x8*)(Woutb + (size_t)n * 512 + s * 32 + q * 8);
                accB[nt] = mfma16(af, wb, accB[nt]);
            }
        }
#pragma unroll
        for (int nt = 0; nt < 2; ++nt) {
            const int col = wave * 32 + nt * 16 + c15;
            const float bb = bout[col];
#pragma unroll
            for (int r = 0; r < 4; ++r) {
                const int row = q * 4 + r;
                tb[row * 132 + col] = accB[nt][r] + bb + h1[(size_t)(r0g + row) * 128 + col];
            }
        }
    }
    __syncthreads();

    // LN2 + mask: wave w -> rows w*4 .. w*4+3
#pragma unroll
    for (int rr = 0; rr < 4; ++rr) {
        const int row = wave * 4 + rr;
        const int gr  = r0g + row;
        const float x0 = tb[row * 132 + lane];
        const float x1 = tb[row * 132 + 64 + lane];
        float sm = x0 + x1, sq = x0 * x0 + x1 * x1;
#pragma unroll
        for (int off = 1; off < 64; off <<= 1) { sm += __shfl_xor(sm, off); sq += __shfl_xor(sq, off); }
        const float mu  = sm * (1.0f / 128.0f);
        const float var = sq * (1.0f / 128.0f) - mu * mu;
        const float inv = rsqrtf(var + 1e-5f);
        const float mv  = mask_V[gr];
        out[(size_t)gr * 128 + lane]      = mv * ((x0 - mu) * inv * ln2g[lane]      + ln2b[lane]);
        out[(size_t)gr * 128 + 64 + lane] = mv * ((x1 - mu) * inv * ln2g[64 + lane] + ln2b[64 + lane]);
    }
}

// ---------------------------------------------------------------------------
extern "C" void kernel_launch(void* const* d_in, const int* in_sizes, int n_in,
                              void* d_out, int out_size, void* d_ws, size_t ws_size,
                              hipStream_t stream) {
    const float* h_V         = (const float*)d_in[0];
    const float* h_E         = (const float*)d_in[1];
    const float* mask_V      = (const float*)d_in[2];
    const float* mask_attend = (const float*)d_in[3];
    const float* W1w  = (const float*)d_in[4];
    const float* W1bb = (const float*)d_in[5];
    const float* W2w  = (const float*)d_in[6];
    const float* W2bb = (const float*)d_in[7];
    const float* W3w  = (const float*)d_in[8];
    const float* W3bb = (const float*)d_in[9];
    const float* ln1g = (const float*)d_in[10];
    const float* ln1b = (const float*)d_in[11];
    const float* ln2g = (const float*)d_in[12];
    const float* ln2b = (const float*)d_in[13];
    const float* Winw  = (const float*)d_in[14];
    const float* Winbb = (const float*)d_in[15];
    const float* Woutw  = (const float*)d_in[16];
    const float* Woutbb = (const float*)d_in[17];

    char* ws    = (char*)d_ws;
    bf16* wsb   = (bf16*)ws;
    bf16* W1c   = wsb;
    bf16* W2c   = wsb + WS_W2;
    bf16* W3c   = wsb + WS_W3;
    bf16* Winc  = wsb + WS_WIN;
    bf16* Woutc = wsb + WS_WOUT;
    float* h1   = (float*)(ws + WS_H1_OFF);
    bf16* hEb   = (bf16*)(ws + WS_HEB_OFF);

    const long long nE = (long long)in_sizes[1];              // 75,497,472 elements
    const size_t ws_need = (size_t)WS_HEB_OFF + (size_t)nE * 2;

    convert_weights<<<896, 256, 0, stream>>>(W1w, W2w, W3w, Winw, Woutw, wsb);
    if (ws_size >= ws_need) {
        const int nb = (int)((nE + 2047) / 2048);             // 8 elems/thread, 256 thr
        convert_hE<<<nb, 256, 0, stream>>>(h_E, hEb, nE);
        msg_kernel_b<<<4096, 256, 0, stream>>>(h_V, hEb, mask_attend, W1c, W2c, W3c,
                                               W1bb, W2bb, W3bb, ln1g, ln1b, h1);
    } else {
        msg_kernel<<<4096, 256, 0, stream>>>(h_V, h_E, mask_attend, W1c, W2c, W3c,
                                             W1bb, W2bb, W3bb, ln1g, ln1b, h1);
    }
    ffn_kernel<<<256, 256, 0, stream>>>(h1, Winc, Woutc, Winbb, Woutbb,
                                        ln2g, ln2b, mask_V, (float*)d_out);
}